// Round 3
// baseline (568.500 us; speedup 1.0000x reference)
//
#include <hip/hip_runtime.h>
#include <hip/hip_bf16.h>

// GetAffs: seg [1,1,4096,4096] f32 (integer labels), out [8,4096,4096] f32.
// out[o][i][j] = (zeroext(seg)[i+ox][j+oy] == seg[i][j]) ? 1.0f : 0.0f
// OFFSETS: (-1,0),(0,-1),(-2,0),(0,-2),(-4,0),(0,-4),(-8,0),(0,-8)
//
// R5: read-traffic minimization. R3/R4 ruled out store flavor/order as >10%
// levers (the harness fill proves interleaved 1KB writes sustain 6.25 TB/s).
// Remaining honest inefficiency: halo reads. BAND 8->16 (512-thr blocks,
// half-row): read amp 2.0x -> 1.5x. XCD-chunked block order: consecutive
// bands on the SAME XCD so halo rows can be L2-hits from the neighbor band.
// NT stores + plane-outer vertical stores kept from R4.

#define IMG_H 4096
#define IMG_W 4096
#define BAND  16
#define HALO  8

typedef float floatx4 __attribute__((ext_vector_type(4)));

__device__ __forceinline__ float4 ld4(const float* p) { return *(const float4*)p; }

__device__ __forceinline__ void st4_nt(float* p, float4 v) {
    floatx4 x = { v.x, v.y, v.z, v.w };
    __builtin_nontemporal_store(x, (floatx4*)p);
}

__device__ __forceinline__ float4 eq4(float4 a, float4 b) {
    return make_float4(a.x == b.x ? 1.0f : 0.0f,
                       a.y == b.y ? 1.0f : 0.0f,
                       a.z == b.z ? 1.0f : 0.0f,
                       a.w == b.w ? 1.0f : 0.0f);
}

__global__ __launch_bounds__(512, 4) void GetAffs_83416854823610_kernel(
        const float* __restrict__ seg, float* __restrict__ out) {
    // 512 blocks: band (0..255) x col-half (0..1). XCD-chunked so consecutive
    // bands run on the same XCD (8 XCDs, 64 blocks per chunk).
    const int bid  = blockIdx.x;
    const int nbid = (bid & 7) * (512 / 8) + (bid >> 3);
    const int cb   = nbid & 1;          // which half-row (2048 cols)
    const int band = nbid >> 1;         // 16-row band index

    const int j  = (cb << 11) + (threadIdx.x << 2);  // this thread's 4 columns
    const int i0 = band * BAND;                      // first band row
    const float4 zero4 = make_float4(0.f, 0.f, 0.f, 0.f);
    const size_t HW = (size_t)IMG_H * IMG_W;

    // c[k] = seg row (i0 - 8 + k), k=0..23: 8 halo rows + 16 band rows.
    float4 c[HALO + BAND];

    // ---- Phase 1: stage rows; compute+store horizontal planes for band rows.
#pragma unroll
    for (int k = 0; k < HALO + BAND; ++k) {
        const int r = i0 - HALO + k;
        c[k] = (r >= 0) ? ld4(seg + (size_t)r * IMG_W + j) : zero4;
        if (k >= HALO) {                       // band row i = r
            const float* row = seg + (size_t)r * IMG_W;
            const float4 cc = c[k];
            const float4 l1 = (j >= 4) ? ld4(row + j - 4) : zero4;  // cols j-4..j-1
            const float4 l2 = (j >= 8) ? ld4(row + j - 8) : zero4;  // cols j-8..j-5
            const float4 h1 = make_float4(l1.w, cc.x, cc.y, cc.z);  // cols j-1..j+2
            const float4 h2 = make_float4(l1.z, l1.w, cc.x, cc.y);  // cols j-2..j+1
            const size_t base = (size_t)r * IMG_W + (size_t)j;
            st4_nt(out + 1 * HW + base, eq4(h1, cc));   // ( 0,-1)
            st4_nt(out + 3 * HW + base, eq4(h2, cc));   // ( 0,-2)
            st4_nt(out + 5 * HW + base, eq4(l1, cc));   // ( 0,-4)
            st4_nt(out + 7 * HW + base, eq4(l2, cc));   // ( 0,-8)
        }
    }

    // ---- Phase 2: vertical planes, plane-outer, pure register -> store.
#define VPLANE(P, D)                                                        \
    _Pragma("unroll")                                                       \
    for (int u = 0; u < BAND; ++u) {                                        \
        const size_t base = (size_t)(i0 + u) * IMG_W + (size_t)j;           \
        st4_nt(out + (P) * HW + base, eq4(c[HALO + u - (D)], c[HALO + u])); \
    }

    VPLANE(0, 1)   // (-1, 0)
    VPLANE(2, 2)   // (-2, 0)
    VPLANE(4, 4)   // (-4, 0)
    VPLANE(6, 8)   // (-8, 0)
#undef VPLANE
}

extern "C" void kernel_launch(void* const* d_in, const int* in_sizes, int n_in,
                              void* d_out, int out_size, void* d_ws, size_t ws_size,
                              hipStream_t stream) {
    const float* seg = (const float*)d_in[0];
    float* out = (float*)d_out;
    dim3 grid(512);    // 256 bands x 2 col-halves, XCD-chunked in-kernel
    dim3 block(512);
    GetAffs_83416854823610_kernel<<<grid, block, 0, stream>>>(seg, out);
}